// Round 4
// baseline (158.457 us; speedup 1.0000x reference)
//
#include <hip/hip_runtime.h>
#include <math.h>

// DSHW — R10: single fused kernel.
//   * Epilogue folded into the scan block: fcast/Ic/wc/e/T/S are per-series
//     local (own registers + own sW column) -> no ws round-trip, no second
//     dispatch, no inter-kernel gap.
//   * fcast staged in the freed sY (yhat already flushed), float4 flush.
//   * aur trick: carry aur = al*u only (uring dropped, -16 VGPR); D uses
//     ga/al, om/al folded coefficients.
// R9 post-mortem: issue ~132 cyc/step, stall ~228 invariant across
// structures; total-scan = 61.5us constant -> attack the overhead part that
// is ours (epilogue dispatch + ws traffic). Predicted total 139 -> ~125.

#define P1c   24
#define P2c   168
#define NSTEP 512
#define BSc   64
#define NFc   16
#define MAXH  336
#define NT    32
#define NSERIES 1024

#define OFF_FC   0
#define OFF_YH   (BSc * MAXH * NFc)
#define OFF_E    (OFF_YH + BSc * NSTEP * NFc)
#define OFF_IC   (OFF_E  + BSc * NSTEP * NFc)
#define OFF_WC   (OFF_IC + BSc * P1c * NFc)
#define OFF_T    (OFF_WC + BSc * P2c * NFc)
#define OFF_S    (OFF_T  + BSc * NFc)

__device__ __forceinline__ double nrcp(double a) {      // 2-NR (init only)
    double x = __builtin_amdgcn_rcp(a);
    x = fma(fma(-a, x, 1.0), x, x);
    x = fma(fma(-a, x, 1.0), x, x);
    return x;
}

__device__ __forceinline__ double nrcp1(double a) {     // 1-NR (loop)
    double x = __builtin_amdgcn_rcp(a);
    x = fma(fma(-a, x, 1.0), x, x);
    return x;
}

__global__ __launch_bounds__(NT, 1)
void dshw_all(const float* __restrict__ y,
              const float* __restrict__ alphas,
              const float* __restrict__ betas,
              const float* __restrict__ gammas,
              const float* __restrict__ omegas,
              float* __restrict__ out)
{
    __shared__ double sW[P2c][NT];                    // 42 KiB
    __shared__ __align__(16) float sY[NSTEP][NT];     // 64 KiB (y -> yhat -> fc)

    const int tid = threadIdx.x;
    const int g   = blockIdx.x * NT + tid;
    const int bb  = g >> 4;
    const int f   = g & 15;
    const int chunk = blockIdx.x * 2;                 // first batch of this block

    // ---------------- stage y into LDS (coalesced) ----------------
    const float4* __restrict__ y4 =
        (const float4*)(y + (size_t)chunk * NSTEP * NFc);
    #pragma unroll 8
    for (int i = tid; i < (NSTEP * NT) / 4; i += NT) {
        float4 v = y4[i];
        const int e0 = i << 2;            // element index in 2-batch chunk
        const int f0 = e0 & 15;           // feature (multiple of 4)
        const int r  = e0 >> 4;           // bl*512 + step
        const int st = r & (NSTEP - 1);
        const int bl = r >> 9;
        *(float4*)&sY[st][bl * 16 + f0] = v;
    }
    __syncthreads();

    const double al = 1.0 / (1.0 + exp(-(double)alphas[f]));
    const double be = 1.0 / (1.0 + exp(-(double)betas[f]));
    const double ga = 1.0 / (1.0 + exp(-(double)gammas[f]));
    const double om = 1.0 / (1.0 + exp(-(double)omegas[f]));
    const double one_m_al = 1.0 - al, one_m_be = 1.0 - be;
    const double one_p_be = 1.0 + be;
    const double one_m_ga = 1.0 - ga, one_m_om = 1.0 - om;
    const double inv_al = 1.0 / al;
    const double ga_al  = ga * inv_al;    // D consumes aur = al*u
    const double om_al  = om * inv_al;

    // ---------------- init (all LDS reads, own column) ----------------
    double Icr[P1c];
    double sum48 = 0.0;
    #pragma unroll
    for (int ph = 0; ph < P1c; ++ph) {
        double v0 = (double)sY[ph][tid];
        double v1 = (double)sY[ph + P1c][tid];
        Icr[ph] = 0.5 * (v0 + v1);
        sum48 += v0 + v1;
    }
    const double inv_mean48 = 48.0 * nrcp(sum48);
    #pragma unroll
    for (int ph = 0; ph < P1c; ++ph) Icr[ph] *= inv_mean48;

    double sa = 0.0, sb = 0.0;
    #pragma unroll 8
    for (int i = 0; i < P2c; ++i) {
        double v0 = (double)sY[i][tid];
        double v1 = (double)sY[i + P2c][tid];
        sW[i][tid] = 0.5 * (v0 + v1);
        sa += v0; sb += v1;
    }
    const double mean336     = (sa + sb) * (1.0 / 336.0);
    const double inv_mean336 = nrcp(mean336);
    #pragma unroll
    for (int ph = 0; ph < P1c; ++ph) {
        double rI = inv_mean336 * nrcp(Icr[ph]);   // 24 recips instead of 168
        #pragma unroll
        for (int r = 0; r < 7; ++r) {
            const int i = ph + 24 * r;
            sW[i][tid] = sW[i][tid] * rI;
        }
    }

    double tt0 = 0.5 * ((sa - sb) * (1.0 / (168.0 * 168.0)) +
                        ((double)sY[P2c - 1][tid] - (double)sY[0][tid]) * (1.0 / 168.0));
    double ss0 = mean336 - 168.5 * tt0;

    // serial-core carried state: spt_k and sprev = snew_{k-1}
    double spt   = ss0 + tt0;
    double sprev = ss0;

    // ---------------- scan ----------------
    double yring[12], wring[24], aring[8], iwring[6], snring[3];

    #pragma unroll
    for (int k = 0; k < 12; ++k) yring[k] = (double)sY[k][tid];
    #pragma unroll
    for (int k = 0; k < 12; ++k) wring[k] = sW[k][tid];
    // B warmup: steps 0..3 (2-NR here, off-loop)
    #pragma unroll
    for (int m = 0; m < 4; ++m) {
        double iw  = Icr[m] * wring[m];
        double inv = nrcp(iw);
        iwring[m % 6] = iw;
        aring[m % 8]  = (al * yring[m % 12]) * inv;
    }

    int i2r = 12;   // LDS read phase (s+12) % 168
    int i2w = 0;    // LDS write phase (s-2) % 168

    // ---- group 0 (s0 = 0): D guarded for j < 2 ----
    #pragma unroll
    for (int j = 0; j < 24; ++j) {
        const int s = j;
        // C (serial core: spt -> snew -> sptn, 2 dependent fma)
        double snew = fma(one_m_al, spt, aring[j % 8]);
        double h    = fma(one_m_be, spt, -sprev);
        double yhat = spt * iwring[j % 6];
        double sptn = fma(one_p_be, snew, h);
        sY[s][tid] = (float)yhat;            // recycle: row s is dead
        snring[j % 3] = snew;
        sprev = snew; spt = sptn;
        // A
        wring[(j + 12) % 24] = sW[i2r][tid];
        i2r = (i2r + 1 == P2c) ? 0 : i2r + 1;
        yring[j % 12] = (double)sY[s + 12][tid];
        // B (step s+4)
        {
            double iw2  = Icr[(j + 4) % 24] * wring[(j + 4) % 24];
            double inv2 = nrcp1(iw2);
            iwring[(j + 4) % 6] = iw2;
            aring[(j + 4) % 8]  = (al * yring[(j + 4) % 12]) * inv2;
        }
        // D (step s-2)
        if (j >= 2) {
            double r   = nrcp1(snring[(j + 1) % 3]);
            double x   = aring[(j + 6) % 8] * r;
            double icO = Icr[(j + 22) % 24];
            double wcO = wring[(j + 22) % 24];
            Icr[(j + 22) % 24] = icO * fma(ga_al, x, one_m_ga);
            sW[i2w][tid] = wcO * fma(om_al, x, one_m_om);
            i2w = (i2w + 1 == P2c) ? 0 : i2w + 1;
        }
    }

    // ---- steady groups: s0 = 24..480 ----
    for (int s0 = 24; s0 <= 480; s0 += 24) {
        #pragma unroll
        for (int j = 0; j < 24; ++j) {
            const int s = s0 + j;
            // C
            double snew = fma(one_m_al, spt, aring[j % 8]);
            double h    = fma(one_m_be, spt, -sprev);
            double yhat = spt * iwring[j % 6];
            double sptn = fma(one_p_be, snew, h);
            sY[s][tid] = (float)yhat;
            snring[j % 3] = snew;
            sprev = snew; spt = sptn;
            // A
            wring[(j + 12) % 24] = sW[i2r][tid];
            i2r = (i2r + 1 == P2c) ? 0 : i2r + 1;
            int pidx = s + 12; pidx = (pidx < NSTEP) ? pidx : (NSTEP - 1);
            yring[j % 12] = (double)sY[pidx][tid];
            // B (step s+4)
            {
                double iw2  = Icr[(j + 4) % 24] * wring[(j + 4) % 24];
                double inv2 = nrcp1(iw2);
                iwring[(j + 4) % 6] = iw2;
                aring[(j + 4) % 8]  = (al * yring[(j + 4) % 12]) * inv2;
            }
            // D (step s-2)
            {
                double r   = nrcp1(snring[(j + 1) % 3]);
                double x   = aring[(j + 6) % 8] * r;
                double icO = Icr[(j + 22) % 24];
                double wcO = wring[(j + 22) % 24];
                Icr[(j + 22) % 24] = icO * fma(ga_al, x, one_m_ga);
                sW[i2w][tid] = wcO * fma(om_al, x, one_m_om);
                i2w = (i2w + 1 == P2c) ? 0 : i2w + 1;
            }
        }
    }

    // ---- tail: steps 504..511 ----
    #pragma unroll
    for (int j = 0; j < 8; ++j) {
        const int s = 504 + j;
        double snew = fma(one_m_al, spt, aring[j % 8]);
        double h    = fma(one_m_be, spt, -sprev);
        double yhat = spt * iwring[j % 6];
        double sptn = fma(one_p_be, snew, h);
        sY[s][tid] = (float)yhat;
        snring[j % 3] = snew;
        sprev = snew; spt = sptn;
        if (j < 4) {   // B for steps 508..511
            double iw2  = Icr[(j + 4) % 24] * wring[(j + 4) % 24];
            double inv2 = nrcp1(iw2);
            iwring[(j + 4) % 6] = iw2;
            aring[(j + 4) % 8]  = (al * yring[(j + 4) % 12]) * inv2;
        }
        {   // D for steps 502..509
            double r   = nrcp1(snring[(j + 1) % 3]);
            double x   = aring[(j + 6) % 8] * r;
            double icO = Icr[(j + 22) % 24];
            double wcO = wring[(j + 22) % 24];
            Icr[(j + 22) % 24] = icO * fma(ga_al, x, one_m_ga);
            sW[i2w][tid] = wcO * fma(om_al, x, one_m_om);
            i2w = (i2w + 1 == P2c) ? 0 : i2w + 1;
        }
    }
    // drain D: step 510, step 511
    {
        double r   = nrcp1(snring[0]);
        double x   = aring[6] * r;
        double icO = Icr[6], wcO = wring[6];
        Icr[6] = icO * fma(ga_al, x, one_m_ga);
        sW[i2w][tid] = wcO * fma(om_al, x, one_m_om);
        i2w = (i2w + 1 == P2c) ? 0 : i2w + 1;
    }
    {
        double r   = nrcp1(snring[1]);
        double x   = aring[7] * r;
        double icO = Icr[7], wcO = wring[7];
        Icr[7] = icO * fma(ga_al, x, one_m_ga);
        sW[i2w][tid] = wcO * fma(om_al, x, one_m_om);
    }

    // reconstruct (ss, tt)
    const double ss_f = sprev;          // snew_511
    const double tt_f = spt - sprev;    // tnew_511

    // ---------------- fused epilogue ----------------
    // scalar state outputs
    out[OFF_T + bb * NFc + f] = (float)tt_f;
    out[OFF_S + bb * NFc + f] = (float)ss_f;

    // Ic (rolled by +8), per-thread scattered (24 stores)
    {
        float* __restrict__ ic_o = out + OFF_IC + (size_t)bb * P1c * NFc + f;
        #pragma unroll
        for (int j2 = 0; j2 < P1c; ++j2)
            ic_o[j2 * NFc] = (float)Icr[(j2 + 8) % P1c];
    }
    // wc (rolled by +8), per-thread scattered (168 stores)
    {
        float* __restrict__ wc_o = out + OFF_WC + (size_t)bb * P2c * NFc + f;
        #pragma unroll 8
        for (int j2 = 0; j2 < P2c; ++j2) {
            int p = j2 + 8; if (p >= P2c) p -= P2c;
            wc_o[j2 * NFc] = (float)sW[p][tid];
        }
    }

    // yhat + e flush (coalesced float4; y re-read from global, L2-hot)
    __syncthreads();
    float* __restrict__ yho = out + OFF_YH + (size_t)chunk * NSTEP * NFc;
    float* __restrict__ eo  = out + OFF_E  + (size_t)chunk * NSTEP * NFc;
    #pragma unroll 4
    for (int i = tid; i < (NSTEP * NT) / 4; i += NT) {
        const int e0 = i << 2;
        const int f0 = e0 & 15;
        const int r  = e0 >> 4;
        const int st = r & (NSTEP - 1);
        const int bl = r >> 9;
        float4 yh4 = *(const float4*)&sY[st][bl * 16 + f0];
        float4 yv4 = y4[i];
        ((float4*)yho)[i] = yh4;
        float4 ev;
        ev.x = yv4.x - yh4.x; ev.y = yv4.y - yh4.y;
        ev.z = yv4.z - yh4.z; ev.w = yv4.w - yh4.w;
        ((float4*)eo)[i] = ev;
    }
    __syncthreads();

    // fcast staged into sY[k][tid] (rows 0..335), then float4 flush
    for (int m = 0; m < MAXH / P1c; ++m) {          // 14 groups of 24
        #pragma unroll
        for (int j2 = 0; j2 < P1c; ++j2) {
            const int k = m * P1c + j2;
            int p = k + 8;
            if (p >= P2c) p -= P2c;
            if (p >= P2c) p -= P2c;                 // k+8 < 344 -> at most 2 subtracts
            double cb = Icr[(j2 + 8) % P1c];
            double cc = sW[p][tid];
            double ca = fma((double)(k + 1), tt_f, ss_f);
            sY[k][tid] = (float)(ca * cb * cc);
        }
    }
    __syncthreads();
    float* __restrict__ fco = out + OFF_FC + (size_t)chunk * MAXH * NFc;
    #pragma unroll 4
    for (int i = tid; i < (2 * MAXH * NFc) / 4; i += NT) {   // 2688 float4s
        const int e0 = i << 2;
        const int f0 = e0 & 15;
        const int r  = e0 >> 4;                     // [0, 672)
        const int bl = (r >= MAXH) ? 1 : 0;
        const int st = r - bl * MAXH;
        ((float4*)fco)[i] = *(const float4*)&sY[st][bl * 16 + f0];
    }
}

extern "C" void kernel_launch(void* const* d_in, const int* in_sizes, int n_in,
                              void* d_out, int out_size, void* d_ws, size_t ws_size,
                              hipStream_t stream)
{
    const float* y      = (const float*)d_in[0];
    const float* alphas = (const float*)d_in[1];
    const float* betas  = (const float*)d_in[2];
    const float* gammas = (const float*)d_in[3];
    const float* omegas = (const float*)d_in[4];
    float* out = (float*)d_out;

    hipLaunchKernelGGL(dshw_all, dim3(NSERIES / NT), dim3(NT), 0, stream,
                       y, alphas, betas, gammas, omegas, out);
}